// Round 10
// baseline (85.950 us; speedup 1.0000x reference)
//
#include <hip/hip_runtime.h>

// out[b, c*9+d] = sum_hw fcn[b,c,hw] * kern[c*9+d, hw]; rows L2-normalized.
// B=4096, C=128, D=9, HW=64, all fp32.
//
// Two-kernel (R3 structure, best per-kernel throughput) with fixes:
//  - reduce8 = 3 DPP adds (VALU-only, R7-proven), zero DS ops in main loop
//  - register diet: kern-once (72 regs) + no prefetch buffer + 32-bit idx
//    -> ~115 VGPR natural, under the 128 cap from __launch_bounds__(256,4)
//    (empirical decode R5/R6/R8: 2nd arg = min BLOCKS/CU; 4 blocks x 4 waves
//     = 16 waves/CU -> 128-VGPR cap)
//  - grid 1024 = 4 blocks/CU -> 16 waves/CU (R3..R9 at 8 waves/CU all ~35us;
//    latency-bound, TLP is the missing lever)
// K1: block = 32 channels x 16 rows (2 chunks of 8); thread holds kern[c]
//     in regs across whole kernel; stores raw out + per-(ct,row) sumsq.
// K2: out *= rsqrt(sum of 4 partials + eps).
// Spill tripwire: K1 WRITE_SIZE must stay ~18.6 MB.

constexpr int B_TOT = 4096;
constexpr int C_CH  = 128;
constexpr int D_EMB = 9;
constexpr int THREADS = 256;
constexpr int GPB = 32;   // channels per block
constexpr int RB  = 16;   // rows per block
constexpr int CHK = 8;    // rows per chunk (= lanes per group)

__device__ __forceinline__ float reduce8_hw(float p) {
    // sum over the 8-lane group, VALU-only DPP (verified R7: passes)
    p += __int_as_float(__builtin_amdgcn_mov_dpp(__float_as_int(p), 0xB1,  0xf, 0xf, true)); // xor1 (quad_perm [1,0,3,2])
    p += __int_as_float(__builtin_amdgcn_mov_dpp(__float_as_int(p), 0x4E,  0xf, 0xf, true)); // xor2 (quad_perm [2,3,0,1])
    p += __int_as_float(__builtin_amdgcn_mov_dpp(__float_as_int(p), 0x141, 0xf, 0xf, true)); // xor4 (half-row mirror, 8 lanes)
    return p;
}

__global__ __launch_bounds__(THREADS, 4)
void esenc_main(const float* __restrict__ fcn,
                const float* __restrict__ kern,
                float* __restrict__ out,
                float* __restrict__ partial) {
    __shared__ float red[THREADS];

    const int tid = threadIdx.x;
    const int l   = tid & 7;        // hw-slice lane, later row id within chunk
    const int g   = tid >> 3;       // group 0..31 (channel)
    const int ct  = blockIdx.x & 3;
    const int bt  = blockIdx.x >> 2;
    const unsigned b0 = (unsigned)bt * RB;
    const unsigned c  = (unsigned)(ct * GPB + g);

    const float4* kern4 = (const float4*)kern;
    const float4* f4    = (const float4*)fcn;

    // kern for this channel, loaded ONCE, held across the whole kernel (72 VGPR)
    float4 k0[D_EMB], k1[D_EMB];
#pragma unroll
    for (int d = 0; d < D_EMB; ++d) {
        const unsigned kb = (c * D_EMB + (unsigned)d) * 16u;
        k0[d] = kern4[kb + l];
        k1[d] = kern4[kb + 8u + l];
    }

#pragma unroll
    for (int chk = 0; chk < RB / CHK; ++chk) {
        const unsigned bb = b0 + (unsigned)(chk * CHK);
        float keep[D_EMB];

#pragma unroll
        for (int r = 0; r < CHK; ++r) {
            const unsigned fb = ((bb + (unsigned)r) * C_CH + c) * 16u;
            const float4 a0 = f4[fb + l];
            const float4 a1 = f4[fb + 8u + l];
#pragma unroll
            for (int d = 0; d < D_EMB; ++d) {
                float t;
                t = a0.x * k0[d].x;
                t = fmaf(a0.y, k0[d].y, t);
                t = fmaf(a0.z, k0[d].z, t);
                t = fmaf(a0.w, k0[d].w, t);
                t = fmaf(a1.x, k1[d].x, t);
                t = fmaf(a1.y, k1[d].y, t);
                t = fmaf(a1.z, k1[d].z, t);
                t = fmaf(a1.w, k1[d].w, t);
                t = reduce8_hw(t);
                if (l == r) keep[d] = t;
            }
        }

        // lane l owns row bb+l: store raw 9 floats + accumulate sumsq
        float* op = out + (size_t)(bb + l) * (C_CH * D_EMB) + c * D_EMB;
        float s = 0.0f;
#pragma unroll
        for (int d = 0; d < D_EMB; ++d) {
            op[d] = keep[d];
            s = fmaf(keep[d], keep[d], s);
        }

        if (chk) __syncthreads();          // red[] reuse guard
        red[tid] = s;
        __syncthreads();
        if (tid < CHK) {                   // row tid of this chunk: sum 32 groups
            float t = 0.0f;
#pragma unroll
            for (int gg = 0; gg < GPB; ++gg) t += red[gg * 8 + tid];
            partial[ct * B_TOT + (int)bb + tid] = t;
        }
    }
}

__global__ __launch_bounds__(256)
void esenc_norm(float* __restrict__ out, const float* __restrict__ partial) {
    constexpr int ROW4 = C_CH * D_EMB / 4;             // 288 float4 per row
    constexpr int N4   = B_TOT * ROW4;
    float4* o4 = (float4*)out;
    for (int i = blockIdx.x * blockDim.x + threadIdx.x; i < N4;
         i += gridDim.x * blockDim.x) {
        const int b = i / ROW4;
        const float s = partial[b] + partial[B_TOT + b] +
                        partial[2 * B_TOT + b] + partial[3 * B_TOT + b];
        const float inv = 1.0f / sqrtf(s + 1e-10f);
        float4 v = o4[i];
        v.x *= inv; v.y *= inv; v.z *= inv; v.w *= inv;
        o4[i] = v;
    }
}

extern "C" void kernel_launch(void* const* d_in, const int* in_sizes, int n_in,
                              void* d_out, int out_size, void* d_ws, size_t ws_size,
                              hipStream_t stream) {
    const float* fcn  = (const float*)d_in[0];   // [4096,128,8,8] f32
    const float* kern = (const float*)d_in[1];   // [1,1152,8,8]  f32
    float* out = (float*)d_out;                  // [4096,1152]   f32
    float* partial = (float*)d_ws;               // [4][4096] f32 = 64 KB

    dim3 grid1((B_TOT / RB) * 4), block1(THREADS);   // 1024 blocks
    hipLaunchKernelGGL(esenc_main, grid1, block1, 0, stream, fcn, kern, out, partial);

    dim3 grid2(1024), block2(256);
    hipLaunchKernelGGL(esenc_norm, grid2, block2, 0, stream, out, partial);
}

// Round 11
// 31.573 us; speedup vs baseline: 2.7223x; 2.7223x over previous
//
#include <hip/hip_runtime.h>

// Fused: out[b, c*9+d] = sum_hw fcn[b,c,hw] * kern[c*9+d, hw], row-L2-normalized.
// B=4096, C=128, D=9, HW=64, all fp32. One kernel; fcn read once; out written once.
//
// 16-waves/CU design (R3..R10 all ~8 waves/CU, ~35us, latency-bound):
//  - block = 4 rows x 128 channels, 256 thr = 32 groups x 8 lanes, NCH=4
//  - grid = 1024 = 4 blocks/CU x 4 waves = 16 waves/CU
//  - register inversion vs R7: fcn rows resident (8 float4/ch-iter, read ONCE),
//    kern transient per-d (8 regs) -> ~100 VGPR natural (R7 was ~130)
//  - __launch_bounds__(256,2): empirical cap ~= 256/N = 128 VGPR; N=4 means
//    64-reg cap on this toolchain (R5/R8/R10 all spilled at N=4) - never use.
//  - keep[] zero-init; only lanes l<4 own rows; all lanes' shfl contributions valid
//  - out staged via LDS: 4 contiguous rows -> 1152 float4 coalesced stores
// reduce8 = 3 DPP adds (quad_perm xor1/xor2 + row_half_mirror), zero DS ops.
// Spill tripwire: WRITE_SIZE must stay ~18.5 MB.

constexpr int B_TOT = 4096;
constexpr int C_CH  = 128;
constexpr int D_EMB = 9;
constexpr int THREADS = 256;
constexpr int GPB = 32;   // concurrent channels (groups) per block
constexpr int NCH = 4;    // channel iterations per group
constexpr int RB  = 4;    // rows per block
constexpr int ROWF = C_CH * D_EMB;   // 1152 floats per output row

__device__ __forceinline__ float reduce8_hw(float p) {
    // sum over the 8-lane group, VALU-only DPP (R7-proven)
    p += __int_as_float(__builtin_amdgcn_mov_dpp(__float_as_int(p), 0xB1,  0xf, 0xf, true)); // xor1
    p += __int_as_float(__builtin_amdgcn_mov_dpp(__float_as_int(p), 0x4E,  0xf, 0xf, true)); // xor2
    p += __int_as_float(__builtin_amdgcn_mov_dpp(__float_as_int(p), 0x141, 0xf, 0xf, true)); // xor4 (row_half_mirror)
    return p;
}

__global__ __launch_bounds__(THREADS, 2)
void esenc_fused(const float* __restrict__ fcn,
                 const float* __restrict__ kern,
                 float* __restrict__ out) {
    __shared__ __align__(16) float tile[RB * ROWF];   // 18432 B
    __shared__ float red[4 * RB];                      // 4 waves x 4 rows
    __shared__ float invn[RB];

    const int tid = threadIdx.x;
    const int l   = tid & 7;        // hw-slice lane; rows 0..3 kept by lanes 0..3
    const int g   = tid >> 3;       // group 0..31
    const int w   = tid >> 6;       // wave 0..3
    const unsigned b0 = blockIdx.x * RB;

    const float4* kern4 = (const float4*)kern;
    const float4* f4    = (const float4*)fcn;

    float keep[NCH][D_EMB] = {};    // lanes 4..7 stay zero (shfl contributions valid)

#pragma unroll
    for (int ch = 0; ch < NCH; ++ch) {
        const unsigned c = (unsigned)(ch * GPB + g);

        // fcn rows resident: 4 rows x 2 float4 (read once, 32 VGPR)
        float4 f0[RB], f1[RB];
#pragma unroll
        for (int r = 0; r < RB; ++r) {
            const unsigned fb = ((b0 + (unsigned)r) * C_CH + c) * 16u;
            f0[r] = f4[fb + l];
            f1[r] = f4[fb + 8u + l];
        }

#pragma unroll
        for (int d = 0; d < D_EMB; ++d) {
            const unsigned kb = (c * D_EMB + (unsigned)d) * 16u;
            const float4 k0 = kern4[kb + l];     // transient: 8 VGPR
            const float4 k1 = kern4[kb + 8u + l];
#pragma unroll
            for (int r = 0; r < RB; ++r) {
                float t;
                t = f0[r].x * k0.x;
                t = fmaf(f0[r].y, k0.y, t);
                t = fmaf(f0[r].z, k0.z, t);
                t = fmaf(f0[r].w, k0.w, t);
                t = fmaf(f1[r].x, k1.x, t);
                t = fmaf(f1[r].y, k1.y, t);
                t = fmaf(f1[r].z, k1.z, t);
                t = fmaf(f1[r].w, k1.w, t);
                t = reduce8_hw(t);
                if (l == r) keep[ch][d] = t;
            }
        }
    }

    // row sumsq: lanes l<4 hold row l's 4-channel partial; others contribute 0
    float s = 0.0f;
#pragma unroll
    for (int ch = 0; ch < NCH; ++ch)
#pragma unroll
        for (int d = 0; d < D_EMB; ++d)
            s = fmaf(keep[ch][d], keep[ch][d], s);

    s += __shfl_xor(s, 8,  64);   // reduce over the wave's 8 groups
    s += __shfl_xor(s, 16, 64);
    s += __shfl_xor(s, 32, 64);
    if ((tid & 63) < RB) red[w * RB + l] = s;

    // stage raw results into LDS (lanes l<4 only)
    if (l < RB) {
#pragma unroll
        for (int ch = 0; ch < NCH; ++ch) {
            const int c = ch * GPB + g;
#pragma unroll
            for (int d = 0; d < D_EMB; ++d)
                tile[l * ROWF + c * D_EMB + d] = keep[ch][d];
        }
    }
    __syncthreads();
    if (tid < RB)
        invn[tid] = 1.0f / sqrtf(red[tid] + red[RB + tid] + red[2 * RB + tid]
                                 + red[3 * RB + tid] + 1e-10f);
    __syncthreads();

    // coalesced store: 4 contiguous rows = 1152 float4
    const float4* t4 = (const float4*)tile;
    float4* o4 = (float4*)(out + (size_t)b0 * ROWF);
#pragma unroll
    for (int j = 0; j < (RB * ROWF / 4) / THREADS + 1; ++j) {
        const int i = tid + j * THREADS;
        if (i < RB * ROWF / 4) {
            const float inv = invn[i / (ROWF / 4)];
            float4 v = t4[i];
            v.x *= inv; v.y *= inv; v.z *= inv; v.w *= inv;
            o4[i] = v;
        }
    }
}

extern "C" void kernel_launch(void* const* d_in, const int* in_sizes, int n_in,
                              void* d_out, int out_size, void* d_ws, size_t ws_size,
                              hipStream_t stream) {
    const float* fcn  = (const float*)d_in[0];   // [4096,128,8,8] f32
    const float* kern = (const float*)d_in[1];   // [1,1152,8,8]  f32
    float* out = (float*)d_out;                  // [4096,1152]   f32

    dim3 grid(B_TOT / RB), block(THREADS);       // 1024 blocks
    hipLaunchKernelGGL(esenc_fused, grid, block, 0, stream, fcn, kern, out);
}